// Round 8
// baseline (99.825 us; speedup 1.0000x reference)
//
#include <hip/hip_runtime.h>

#define H 200
#define NP 64
#define NIMG 24
#define NB 8
#define NPIX (H*H)
#define GSTEP (2.0f/199.0f)
#define SPI 20          // strip-halves per image (10 y-strips x 2 x-halves)
#define NWORK (NIMG*SPI)  // 480 blocks; LDS 56.4KB -> 2 blocks/CU -> 512 capacity >= 480 (no deadlock)

typedef __fp16 h2 __attribute__((ext_vector_type(2)));

__device__ __forceinline__ float fdot2f(unsigned int a, unsigned int b, float c) {
  h2 ha = __builtin_bit_cast(h2, a);
  h2 hb = __builtin_bit_cast(h2, b);
#if __has_builtin(__builtin_amdgcn_fdot2)
  return __builtin_amdgcn_fdot2(ha, hb, c, false);
#else
  return c + (float)ha.x * (float)hb.x + (float)ha.y * (float)hb.y;
#endif
}

__device__ __forceinline__ unsigned int pk2(float lo, float hi) {
#if __has_builtin(__builtin_amdgcn_cvt_pkrtz)
  h2 h = __builtin_amdgcn_cvt_pkrtz(lo, hi);
  return __builtin_bit_cast(unsigned int, h);
#else
  h2 h; h.x = (__fp16)lo; h.y = (__fp16)hi;
  return __builtin_bit_cast(unsigned int, h);
#endif
}

__device__ __forceinline__ float agentLoadF(const float* p) {
  return __hip_atomic_load(p, __ATOMIC_RELAXED, __HIP_MEMORY_SCOPE_AGENT);
}

// Single kernel: one block per (img, y-strip of 20 rows, x-half of 100 cols).
// A: tables (f32 + f16 packs). B: waves 0-1 mask GEMM (reg-held), waves 2-3 score GEMM.
// software grid barrier (atomic counter, all 480 blocks co-resident by capacity).
// C: normalize reg-held mask -> single out write; blocks 0..7 reduce scores.
__global__ __launch_bounds__(256, 2) void prs_all(
    const float* __restrict__ cam,   // (8,3,2,3)
    const float* __restrict__ cloud, // (8,64,3)
    const float* __restrict__ mt,    // (8,3,200,200)
    const float* __restrict__ blur,  // (8,64)
    const float* __restrict__ b3,    // (8,3)
    const float* __restrict__ b2,    // (8,3,2)
    float* __restrict__ out,
    float* __restrict__ ws_msum,     // [512]
    float* __restrict__ ws_scr,      // [NWORK][64]
    unsigned int* __restrict__ counter)
{
  __shared__ float ex[NP*100];          // [n][x] f32          25600 B
  __shared__ float eys[20*NP];          // [y][n] f32           5120 B
  __shared__ unsigned int exp2_[32*100];// [n2][x] f16-pair    12800 B
  __shared__ unsigned int eyp2[32*20];  // [n2][y] f16-pair     2560 B
  __shared__ unsigned int eyy[NP*12];   // [n][y2] f16-pair     3072 B (10 used)
  __shared__ unsigned int Mp[100*12];   // [x][y2] f16-pair     4800 B (10 used)
  __shared__ float cinv[100];
  __shared__ float Sy[NP];
  __shared__ float ptx[NP], pty[NP], i2s[NP];
  __shared__ float red[256];

  const int tid = threadIdx.x;
  const int blk = blockIdx.x;
  const int img = blk / SPI;
  const int rem = blk - img * SPI;
  const int strip = rem >> 1;
  const int xh = rem & 1;
  const int b = img / 3;
  const int c = img - 3 * b;
  const int ys0 = strip * 20;
  const int xb = xh * 100;

  // ---- A1: point params ----
  if (tid < NP) {
    int n = tid;
    float p0 = cloud[(b*NP + n)*3 + 0] + b3[b*3 + 0];
    float p1 = cloud[(b*NP + n)*3 + 1] + b3[b*3 + 1];
    float p2 = cloud[(b*NP + n)*3 + 2] + b3[b*3 + 2];
    const float* cc = cam + ((b*3 + c)*2)*3;
    float px = cc[0]*p0 + cc[1]*p1 + cc[2]*p2 - b2[(b*3 + c)*2 + 0];
    float py = cc[3]*p0 + cc[4]*p1 + cc[5]*p2 - b2[(b*3 + c)*2 + 1];
    ptx[n] = fminf(fmaxf(px * 0.01f, -1.0f), 1.0f);
    pty[n] = fminf(fmaxf(py * 0.01f, -1.0f), 1.0f);
    float s = blur[b*NP + n];
    i2s[n] = 1.0f / (2.0f * s * s);
  }
  __syncthreads();

  // ---- A2: eys (strip), ex (x-half), Syp (full-y, into red) ----
  for (int e = tid; e < 20*NP; e += 256) {
    int y = e >> 6, n = e & 63;
    float d = (-1.0f + (ys0 + y)*GSTEP) - pty[n];
    eys[y*NP + n] = __expf(-d*d*i2s[n]);
  }
  for (int e = tid; e < NP*100; e += 256) {
    int n = e / 100, x = e - n*100;
    float d = (-1.0f + (xb + x)*GSTEP) - ptx[n];
    ex[n*100 + x] = __expf(-d*d*i2s[n]);
  }
  {
    int n = tid & 63, g = tid >> 6;
    float pyv = pty[n], iv = i2s[n];
    float s = 0.0f;
    for (int y = g*50; y < g*50 + 50; ++y) {
      float d = (-1.0f + y*GSTEP) - pyv;
      s += __expf(-d*d*iv);
    }
    red[g*NP + n] = s;
  }
  __syncthreads();

  // ---- A3: f16 packs + M staging + Sy reduce ----
  for (int e = tid; e < 3200; e += 256) {           // exp2_[n2][x]
    int n2 = e / 100, x = e - n2*100;
    exp2_[n2*100 + x] = pk2(ex[(2*n2)*100 + x], ex[(2*n2+1)*100 + x]);
  }
  for (int e = tid; e < 640; e += 256) {            // eyp2[n2][y]
    int n2 = e / 20, y = e - n2*20;
    eyp2[n2*20 + y] = pk2(eys[y*NP + 2*n2], eys[y*NP + 2*n2 + 1]);
  }
  for (int e = tid; e < 640; e += 256) {            // eyy[n][y2]
    int n = e / 10, y2 = e - n*10;
    eyy[n*12 + y2] = pk2(eys[(2*y2)*NP + n], eys[(2*y2+1)*NP + n]);
  }
  for (int e = tid; e < 1000; e += 256) {           // Mp[x][y2]
    int y2 = e / 100, x = e - y2*100;
    const float* mb = mt + img*NPIX + (ys0 + 2*y2)*H + xb + x;
    Mp[x*12 + y2] = pk2(mb[0], mb[H]);
  }
  if (tid < NP)
    Sy[tid] = red[tid] + red[NP + tid] + red[2*NP + tid] + red[3*NP + tid];
  __syncthreads();

  // ---- A4: cinv (all f32) ----
  if (tid < 100) {
    float s = 0.0f;
    for (int n = 0; n < NP; ++n) s += ex[n*100 + tid] * Sy[n];
    cinv[tid] = 1.0f / fmaxf(s, 1e-8f);
  }
  __syncthreads();

  // ---- B: wave 0-1 mask GEMM (reg-held), wave 2-3 score GEMM ----
  float macc[4][4];
  int x0 = 0, y0 = 0;
  if (tid < 128) {
    float msl = 0.0f;
    if (tid < 125) {
      int yg = tid / 25;
      int xg = tid - yg*25;
      x0 = xg*4; y0 = yg*4;
      #pragma unroll
      for (int i = 0; i < 4; ++i)
        #pragma unroll
        for (int j = 0; j < 4; ++j) macc[i][j] = 0.0f;
      for (int n2 = 0; n2 < 32; ++n2) {
        uint4 eyv = *(uint4*)&eyp2[n2*20 + y0];
        uint4 exv = *(uint4*)&exp2_[n2*100 + x0];
        macc[0][0]=fdot2f(eyv.x,exv.x,macc[0][0]); macc[0][1]=fdot2f(eyv.x,exv.y,macc[0][1]);
        macc[0][2]=fdot2f(eyv.x,exv.z,macc[0][2]); macc[0][3]=fdot2f(eyv.x,exv.w,macc[0][3]);
        macc[1][0]=fdot2f(eyv.y,exv.x,macc[1][0]); macc[1][1]=fdot2f(eyv.y,exv.y,macc[1][1]);
        macc[1][2]=fdot2f(eyv.y,exv.z,macc[1][2]); macc[1][3]=fdot2f(eyv.y,exv.w,macc[1][3]);
        macc[2][0]=fdot2f(eyv.z,exv.x,macc[2][0]); macc[2][1]=fdot2f(eyv.z,exv.y,macc[2][1]);
        macc[2][2]=fdot2f(eyv.z,exv.z,macc[2][2]); macc[2][3]=fdot2f(eyv.z,exv.w,macc[2][3]);
        macc[3][0]=fdot2f(eyv.w,exv.x,macc[3][0]); macc[3][1]=fdot2f(eyv.w,exv.y,macc[3][1]);
        macc[3][2]=fdot2f(eyv.w,exv.z,macc[3][2]); macc[3][3]=fdot2f(eyv.w,exv.w,macc[3][3]);
      }
      #pragma unroll
      for (int i = 0; i < 4; ++i)
        #pragma unroll
        for (int j = 0; j < 4; ++j) {
          float v = fminf(macc[i][j], 1.0f);
          macc[i][j] = v;
          msl += v;
        }
    }
    // wave-level reduce of msl (lanes 125..127 hold 0)
    #pragma unroll
    for (int off = 32; off > 0; off >>= 1) msl += __shfl_down(msl, off);
    if ((tid & 63) == 0) red[tid >> 6] = msl;
  } else {
    int st = tid - 128;
    int ng = st >> 3;
    int xt = st & 7;
    int n0 = ng * 4;
    uint4 ea[4], eb4[4]; uint2 ec[4];
    #pragma unroll
    for (int i = 0; i < 4; ++i) {
      const unsigned int* p = &eyy[(n0 + i)*12];
      ea[i]  = *(const uint4*)p;
      eb4[i] = *(const uint4*)(p + 4);
      ec[i]  = *(const uint2*)(p + 8);
    }
    float sacc[4] = {0.0f, 0.0f, 0.0f, 0.0f};
    for (int x = xt; x < 100; x += 8) {
      const unsigned int* q = &Mp[x*12];
      uint4 ma = *(const uint4*)q;
      uint4 mb = *(const uint4*)(q + 4);
      uint2 mc = *(const uint2*)(q + 8);
      float cvx = cinv[x];
      #pragma unroll
      for (int i = 0; i < 4; ++i) {
        float t = 0.0f;
        t = fdot2f(ea[i].x, ma.x, t);  t = fdot2f(ea[i].y, ma.y, t);
        t = fdot2f(ea[i].z, ma.z, t);  t = fdot2f(ea[i].w, ma.w, t);
        t = fdot2f(eb4[i].x, mb.x, t); t = fdot2f(eb4[i].y, mb.y, t);
        t = fdot2f(eb4[i].z, mb.z, t); t = fdot2f(eb4[i].w, mb.w, t);
        t = fdot2f(ec[i].x, mc.x, t);  t = fdot2f(ec[i].y, mc.y, t);
        sacc[i] += t * ex[(n0 + i)*100 + x] * cvx;
      }
    }
    #pragma unroll
    for (int off = 4; off > 0; off >>= 1) {
      #pragma unroll
      for (int i = 0; i < 4; ++i) sacc[i] += __shfl_down(sacc[i], off, 8);
    }
    if (xt == 0) {
      #pragma unroll
      for (int i = 0; i < 4; ++i) ws_scr[blk*NP + n0 + i] = sacc[i];
    }
  }
  __syncthreads();                 // red[0..1] + all ws_scr stores issued
  if (tid == 0) ws_msum[blk] = red[0] + red[1];

  // ---- software grid barrier ----
  __threadfence();                 // release: ws_scr / ws_msum visible device-wide
  __syncthreads();
  if (tid == 0) {
    atomicAdd(counter, 1u);
    while (__hip_atomic_load(counter, __ATOMIC_ACQUIRE, __HIP_MEMORY_SCOPE_AGENT) < NWORK)
      __builtin_amdgcn_s_sleep(2);
  }
  __syncthreads();
  __threadfence();                 // acquire

  // ---- Phase C: normalize reg-held mask, single out write ----
  if (tid == 0) {
    float s = 0.0f;
    for (int i = 0; i < SPI; ++i) s += agentLoadF(&ws_msum[img*SPI + i]);
    red[0] = 1.0f / fmaxf(s, 1e-8f);
  }
  __syncthreads();
  {
    const float inv = red[0];
    if (tid < 125) {
      float* ob = out + img*NPIX;
      #pragma unroll
      for (int i = 0; i < 4; ++i) {
        float4 v;
        v.x = macc[i][0] * inv;
        v.y = macc[i][1] * inv;
        v.z = macc[i][2] * inv;
        v.w = macc[i][3] * inv;
        *(float4*)&ob[(ys0 + y0 + i)*H + xb + x0] = v;
      }
    }
  }
  // blocks 0..7: reduce scores for batch blk
  if (blk < NB && tid < NP) {
    float s = 0.0f;
    for (int cc = 0; cc < 3; ++cc)
      for (int sh = 0; sh < SPI; ++sh)
        s += agentLoadF(&ws_scr[((blk*3 + cc)*SPI + sh)*NP + tid]);
    out[NIMG*NPIX + blk*NP + tid] = s * (1.0f/3.0f);
  }
}

extern "C" void kernel_launch(void* const* d_in, const int* in_sizes, int n_in,
                              void* d_out, int out_size, void* d_ws, size_t ws_size,
                              hipStream_t stream) {
  const float* cam   = (const float*)d_in[0];
  const float* cloud = (const float*)d_in[1];
  const float* mt    = (const float*)d_in[2];
  const float* blur  = (const float*)d_in[3];
  const float* b3    = (const float*)d_in[4];
  const float* b2    = (const float*)d_in[5];
  float* out = (float*)d_out;

  float* ws_msum = (float*)d_ws;                    // [512]
  float* ws_scr  = ws_msum + 512;                   // [480][64]
  unsigned int* counter = (unsigned int*)(ws_scr + NWORK*NP);

  // reset barrier counter every call (graph-legal memset node)
  hipMemsetAsync(counter, 0, sizeof(unsigned int), stream);

  prs_all<<<NWORK, 256, 0, stream>>>(cam, cloud, mt, blur, b3, b2,
                                     out, ws_msum, ws_scr, counter);
}

// Round 9
// 25.457 us; speedup vs baseline: 3.9213x; 3.9213x over previous
//
#include <hip/hip_runtime.h>

#define H 200
#define NP 64
#define NIMG 24
#define NB 8
#define NPIX (H*H)
#define GSTEP (2.0f/199.0f)
#define SPI 40            // strip-halves per image (20 y-strips of 10 rows x 2 x-halves)
#define NWORK (NIMG*SPI)  // 960

typedef __fp16 h2 __attribute__((ext_vector_type(2)));

__device__ __forceinline__ float fdot2f(unsigned int a, unsigned int b, float c) {
  h2 ha = __builtin_bit_cast(h2, a);
  h2 hb = __builtin_bit_cast(h2, b);
#if __has_builtin(__builtin_amdgcn_fdot2)
  return __builtin_amdgcn_fdot2(ha, hb, c, false);
#else
  return c + (float)ha.x * (float)hb.x + (float)ha.y * (float)hb.y;
#endif
}

__device__ __forceinline__ unsigned int pk2(float lo, float hi) {
#if __has_builtin(__builtin_amdgcn_cvt_pkrtz)
  h2 h = __builtin_amdgcn_cvt_pkrtz(lo, hi);
  return __builtin_bit_cast(unsigned int, h);
#else
  h2 h; h.x = (__fp16)lo; h.y = (__fp16)hi;
  return __builtin_bit_cast(unsigned int, h);
#endif
}

// K0: one block per image. Computes projected points/sigma, Sy (full-y sums),
// and f32 colsum -> cinv[200]. Removes all per-image-redundant work from K1.
__global__ __launch_bounds__(256) void prs_pre(
    const float* __restrict__ cam,   // (8,3,2,3)
    const float* __restrict__ cloud, // (8,64,3)
    const float* __restrict__ blur,  // (8,64)
    const float* __restrict__ b3,    // (8,3)
    const float* __restrict__ b2,    // (8,3,2)
    float* __restrict__ ws_pt,       // [NIMG][192] (ptx,pty,i2s)
    float* __restrict__ ws_cinv)     // [NIMG][200]
{
  __shared__ float ptx[NP], pty[NP], i2s[NP], Sy[NP];
  __shared__ float red[256];
  __shared__ float cpart[800];

  const int tid = threadIdx.x;
  const int img = blockIdx.x;
  const int b = img / 3;
  const int c = img - 3*b;

  if (tid < NP) {
    int n = tid;
    float p0 = cloud[(b*NP + n)*3 + 0] + b3[b*3 + 0];
    float p1 = cloud[(b*NP + n)*3 + 1] + b3[b*3 + 1];
    float p2 = cloud[(b*NP + n)*3 + 2] + b3[b*3 + 2];
    const float* cc = cam + ((b*3 + c)*2)*3;
    float px = cc[0]*p0 + cc[1]*p1 + cc[2]*p2 - b2[(b*3 + c)*2 + 0];
    float py = cc[3]*p0 + cc[4]*p1 + cc[5]*p2 - b2[(b*3 + c)*2 + 1];
    float pxv = fminf(fmaxf(px * 0.01f, -1.0f), 1.0f);
    float pyv = fminf(fmaxf(py * 0.01f, -1.0f), 1.0f);
    float s = blur[b*NP + n];
    float iv = 1.0f / (2.0f * s * s);
    ptx[n] = pxv; pty[n] = pyv; i2s[n] = iv;
    ws_pt[img*192 + n]       = pxv;
    ws_pt[img*192 + 64 + n]  = pyv;
    ws_pt[img*192 + 128 + n] = iv;
  }
  __syncthreads();

  // Sy partials: 64 n x 4 y-groups of 50
  {
    int n = tid & 63, g = tid >> 6;
    float pyv = pty[n], iv = i2s[n];
    float s = 0.0f;
    for (int y = g*50; y < g*50 + 50; ++y) {
      float d = (-1.0f + y*GSTEP) - pyv;
      s += __expf(-d*d*iv);
    }
    red[g*NP + n] = s;
  }
  __syncthreads();
  if (tid < NP)
    Sy[tid] = red[tid] + red[NP + tid] + red[2*NP + tid] + red[3*NP + tid];
  __syncthreads();

  // colsum partials: 200 x x 4 n-quarters of 16
  for (int e = tid; e < 800; e += 256) {
    int x = e >> 2, sub = e & 3;
    float gx = -1.0f + x*GSTEP;
    float s = 0.0f;
    for (int k = 0; k < 16; ++k) {
      int n = sub*16 + k;
      float d = gx - ptx[n];
      s += __expf(-d*d*i2s[n]) * Sy[n];
    }
    cpart[e] = s;
  }
  __syncthreads();
  if (tid < 200) {
    float s = cpart[tid*4] + cpart[tid*4+1] + cpart[tid*4+2] + cpart[tid*4+3];
    ws_cinv[img*200 + tid] = 1.0f / fmaxf(s, 1e-8f);
  }
}

// K1: one block per (img, 10-row y-strip, 100-col x-half). 960 blocks, 4/CU.
// waves 0-1: f32 mask GEMM (2y x 4x tiles), write unnormalized out + msum.
// waves 2-3: score GEMM: t[n,x] = sum_y2 dot2(eyy, Mp); fold f32 ex*cinv.
__global__ __launch_bounds__(256, 4) void prs_main(
    const float* __restrict__ mt,    // (8,3,200,200)
    const float* __restrict__ ws_pt,
    const float* __restrict__ ws_cinv,
    float* __restrict__ out,
    float* __restrict__ ws_msum,     // [NWORK]
    float* __restrict__ ws_scr)      // [NWORK][64]
{
  __shared__ float ex[NP*100];          // [n][x] f32        25600 B
  __shared__ float eys[10*NP];          // [y][n] f32         2560 B
  __shared__ float eyt[NP*12];          // [n][y] f32         3072 B
  __shared__ unsigned int eyy[NP*8];    // [n][y2] f16-pair   2048 B (5 used)
  __shared__ unsigned int Mp[100*8];    // [x][y2] f16-pair   3200 B (5 used)
  __shared__ float cinv[100];
  __shared__ float ptx[NP], pty[NP], i2s[NP];
  __shared__ float red2[2];

  const int tid = threadIdx.x;
  const int blk = blockIdx.x;
  const int img = blk / SPI;
  const int rem = blk - img * SPI;
  const int strip = rem >> 1;
  const int xh = rem & 1;
  const int ys0 = strip * 10;
  const int xb = xh * 100;

  if (tid < NP) {
    ptx[tid] = ws_pt[img*192 + tid];
    pty[tid] = ws_pt[img*192 + 64 + tid];
    i2s[tid] = ws_pt[img*192 + 128 + tid];
  }
  if (tid >= 128 && tid < 228) cinv[tid - 128] = ws_cinv[img*200 + xb + (tid - 128)];
  __syncthreads();

  // eys[10][64]
  for (int e = tid; e < 10*NP; e += 256) {
    int y = e >> 6, n = e & 63;
    float d = (-1.0f + (ys0 + y)*GSTEP) - pty[n];
    eys[y*NP + n] = __expf(-d*d*i2s[n]);
  }
  // ex[64][100] f32
  {
    int n = tid >> 2;
    int x0 = (tid & 3) * 25;
    float pxv = ptx[n], iv = i2s[n];
    for (int k = 0; k < 25; ++k) {
      int x = x0 + k;
      float d = (-1.0f + (xb + x)*GSTEP) - pxv;
      ex[n*100 + x] = __expf(-d*d*iv);
    }
  }
  __syncthreads();

  // packs
  for (int e = tid; e < 640; e += 256) {        // eyt[n][y]
    int n = e / 10, y = e - n*10;
    eyt[n*12 + y] = eys[y*NP + n];
  }
  for (int e = tid; e < 320; e += 256) {        // eyy[n][y2]
    int n = e / 5, y2 = e - n*5;
    eyy[n*8 + y2] = pk2(eys[(2*y2)*NP + n], eys[(2*y2+1)*NP + n]);
  }
  for (int e = tid; e < 500; e += 256) {        // Mp[x][y2]
    int y2 = e / 100, x = e - y2*100;
    const float* mb = mt + img*NPIX + (ys0 + 2*y2)*H + xb + x;
    Mp[x*8 + y2] = pk2(mb[0], mb[H]);
  }
  __syncthreads();

  if (tid < 128) {
    // ---- mask GEMM: 125 threads, 2y x 4x f32 tiles over 10x100 ----
    float msl = 0.0f;
    if (tid < 125) {
      int yg = tid / 25;
      int xg = tid - yg*25;
      int y0 = yg*2, x0 = xg*4;
      float acc[2][4];
      #pragma unroll
      for (int i = 0; i < 2; ++i)
        #pragma unroll
        for (int j = 0; j < 4; ++j) acc[i][j] = 0.0f;
      for (int n = 0; n < NP; ++n) {
        float4 exv = *(float4*)&ex[n*100 + x0];
        float2 eyv = *(float2*)&eyt[n*12 + y0];
        acc[0][0] += eyv.x*exv.x; acc[0][1] += eyv.x*exv.y;
        acc[0][2] += eyv.x*exv.z; acc[0][3] += eyv.x*exv.w;
        acc[1][0] += eyv.y*exv.x; acc[1][1] += eyv.y*exv.y;
        acc[1][2] += eyv.y*exv.z; acc[1][3] += eyv.y*exv.w;
      }
      float* ob = out + img*NPIX;
      #pragma unroll
      for (int i = 0; i < 2; ++i) {
        float4 v;
        v.x = fminf(acc[i][0], 1.0f);
        v.y = fminf(acc[i][1], 1.0f);
        v.z = fminf(acc[i][2], 1.0f);
        v.w = fminf(acc[i][3], 1.0f);
        msl += v.x + v.y + v.z + v.w;
        *(float4*)&ob[(ys0 + y0 + i)*H + xb + x0] = v;
      }
    }
    #pragma unroll
    for (int off = 32; off > 0; off >>= 1) msl += __shfl_down(msl, off);
    if ((tid & 63) == 0) red2[tid >> 6] = msl;
  } else {
    // ---- score GEMM: 128 threads = 16 n-groups x 8 x-lanes ----
    int st = tid - 128;
    int ng = st >> 3;
    int xt = st & 7;
    int n0 = ng * 4;
    uint4 ea[4]; unsigned int ec[4];
    #pragma unroll
    for (int i = 0; i < 4; ++i) {
      ea[i] = *(const uint4*)&eyy[(n0 + i)*8];
      ec[i] = eyy[(n0 + i)*8 + 4];
    }
    float sacc[4] = {0.0f, 0.0f, 0.0f, 0.0f};
    for (int x = xt; x < 100; x += 8) {
      uint4 ma = *(const uint4*)&Mp[x*8];
      unsigned int mc = Mp[x*8 + 4];
      float cvx = cinv[x];
      #pragma unroll
      for (int i = 0; i < 4; ++i) {
        float t = 0.0f;
        t = fdot2f(ea[i].x, ma.x, t);
        t = fdot2f(ea[i].y, ma.y, t);
        t = fdot2f(ea[i].z, ma.z, t);
        t = fdot2f(ea[i].w, ma.w, t);
        t = fdot2f(ec[i],   mc,   t);
        sacc[i] += t * ex[(n0 + i)*100 + x] * cvx;
      }
    }
    #pragma unroll
    for (int off = 4; off > 0; off >>= 1) {
      #pragma unroll
      for (int i = 0; i < 4; ++i) sacc[i] += __shfl_down(sacc[i], off, 8);
    }
    if (xt == 0) {
      #pragma unroll
      for (int i = 0; i < 4; ++i) ws_scr[blk*NP + n0 + i] = sacc[i];
    }
  }
  __syncthreads();
  if (tid == 0) ws_msum[blk] = red2[0] + red2[1];
}

// K2: blocks 0..479 normalize one 20x100 region of out; blocks 480..487 reduce scores.
__global__ __launch_bounds__(256) void prs_finish(
    float* __restrict__ out,
    const float* __restrict__ ws_msum,
    const float* __restrict__ ws_scr)
{
  const int blk = blockIdx.x;
  const int tid = threadIdx.x;
  if (blk < 480) {
    const int img = blk / 20;
    const int rem = blk - img * 20;
    const int strip = rem >> 1;   // 20-row region
    const int xh = rem & 1;
    __shared__ float invs;
    if (tid == 0) {
      float s = 0.0f;
      for (int i = 0; i < SPI; ++i) s += ws_msum[img*SPI + i];
      invs = 1.0f / fmaxf(s, 1e-8f);
    }
    __syncthreads();
    const float inv = invs;
    for (int q = tid; q < 500; q += 256) {   // 20 rows x 25 float4
      int ry = q / 25;
      int rx = q - ry * 25;
      float* p = out + img*NPIX + (strip*20 + ry)*H + xh*100 + rx*4;
      float4 v = *(float4*)p;
      v.x *= inv; v.y *= inv; v.z *= inv; v.w *= inv;
      *(float4*)p = v;
    }
  } else {
    const int bb = blk - 480;
    if (tid < NP) {
      float s = 0.0f;
      for (int cc = 0; cc < 3; ++cc)
        for (int sh = 0; sh < SPI; ++sh)
          s += ws_scr[((bb*3 + cc)*SPI + sh)*NP + tid];
      out[NIMG*NPIX + bb*NP + tid] = s * (1.0f/3.0f);
    }
  }
}

extern "C" void kernel_launch(void* const* d_in, const int* in_sizes, int n_in,
                              void* d_out, int out_size, void* d_ws, size_t ws_size,
                              hipStream_t stream) {
  const float* cam   = (const float*)d_in[0];
  const float* cloud = (const float*)d_in[1];
  const float* mt    = (const float*)d_in[2];
  const float* blur  = (const float*)d_in[3];
  const float* b3    = (const float*)d_in[4];
  const float* b2    = (const float*)d_in[5];
  float* out = (float*)d_out;

  float* ws_msum = (float*)d_ws;               // [1024]
  float* ws_scr  = ws_msum + 1024;             // [960][64]
  float* ws_pt   = ws_scr + NWORK*NP;          // [24][192]
  float* ws_cinv = ws_pt + NIMG*192;           // [24][200]

  prs_pre<<<NIMG, 256, 0, stream>>>(cam, cloud, blur, b3, b2, ws_pt, ws_cinv);
  prs_main<<<NWORK, 256, 0, stream>>>(mt, ws_pt, ws_cinv, out, ws_msum, ws_scr);
  prs_finish<<<488, 256, 0, stream>>>(out, ws_msum, ws_scr);
}